// Round 1
// 162.879 us; speedup vs baseline: 1.0065x; 1.0065x over previous
//
#include <hip/hip_runtime.h>
#include <hip/hip_bf16.h>

// SizeInvBlock: upsample3x(nearest) -> per-sample dilated 3x3 conv -> maxpool3 -> BN(train) -> relu
// Factorization: conv on the 3x-upsampled image only samples original 32x32 pixels:
//   out[o,y,x] = bias[o] + sum_{ki,kj} T[kikj][o, r_ki(y), c_kj(x)]
//   T[kikj][o,i,j] = sum_c W[o,c,ki,kj] * X[c,i,j]   (one GEMM, 9x fewer FLOPs than direct conv)
// R10: k2 gather specialized on (dh%3, dw%3). The four selector arrays
// (r0/r2/c0/c2) depend ONLY on dh mod 3 / dw mod 3 -> 9 compile-time cases:
// all cndmask selects fold, duplicate pool candidates CSE away, unused
// row/col loads DCE (dh%3==0 kills the B-row loads; dw%3==0 kills b-cols).
// Per-b setup (divides, floordiv3, case idx) precomputed in k0 -> prm table.
//
// ws layout (bytes):
//   [0,      1024)    stats: sum[128], sumsq[128] (f32, atomic; zeroed by k0_all)
//   [1024,   3072)    prm: per-b gather params int[64][8] = {g0,g2,f0,f2,case,...}
//   [4096,   151552)  A bf16 [1152][64]   (m = (ki*3+kj)*128 + o, k = cin)
//   [151552, 8540160) XbT bf16 [64 b][1024 n][64 c]
//   [8540160,159535104) T bf16 [1152][65536]  (n = b*1024 + i*32 + j)

typedef __attribute__((ext_vector_type(8))) short bf16x8;
typedef __attribute__((ext_vector_type(4))) float f32x4;
typedef __attribute__((ext_vector_type(8))) unsigned short us8;

#define BN 65536   // T n-dimension (all 64 samples)

__device__ __forceinline__ unsigned short f2bf(float f) {
    unsigned u = __float_as_uint(f);
    u += 0x7fffu + ((u >> 16) & 1u);
    return (unsigned short)(u >> 16);
}
__device__ __forceinline__ float bf2f(unsigned short s) {
    return __uint_as_float(((unsigned)s) << 16);
}
__device__ __forceinline__ int floordiv3(int t) {
    return (t >= 0) ? (t / 3) : -((2 - t) / 3);
}

// ---- K0: merged prep: X transpose->bf16, W pack->bf16, stats zero, prm ---
// blocks 0..1023: XbT; 1024..1311: A; 1312: stats zero + per-b gather params.
__global__ __launch_bounds__(256) void k0_all(const float* __restrict__ x,
                                              const float* __restrict__ w,
                                              const int* __restrict__ hh,
                                              const int* __restrict__ ww,
                                              unsigned short* __restrict__ xbt,
                                              unsigned short* __restrict__ A,
                                              float* __restrict__ stats,
                                              int* __restrict__ prm) {
    const int bid = blockIdx.x;
    const int tid = threadIdx.x;
    if (bid < 1024) {
        const int n = (bid & 15) * 64 + (tid & 63);
        const int cg = tid >> 6;
        const int b = bid >> 4;
        #pragma unroll
        for (int j2 = 0; j2 < 2; ++j2) {
            int c8 = cg * 2 + j2;                 // 0..7
            us8 r;
            #pragma unroll
            for (int j = 0; j < 8; ++j)
                r[j] = f2bf(x[(((b << 6) + c8 * 8 + j) << 10) + n]);
            *reinterpret_cast<us8*>(xbt + ((size_t)(b << 10) + n) * 64 + c8 * 8) = r;
        }
    } else if (bid < 1312) {
        int gid = (bid - 1024) * 256 + tid;       // < 73728
        int m = gid >> 6, c = gid & 63;
        int kk = m >> 7, o = m & 127;
        A[gid] = f2bf(w[(o * 64 + c) * 9 + kk]);
    } else {
        stats[tid] = 0.f;                          // 256 floats = sum+sumsq
        if (tid < 64) {
            int dh = 96 / hh[tid]; if (dh < 1) dh = 1;
            int dw = 96 / ww[tid]; if (dw < 1) dw = 1;
            int* p = prm + tid * 8;
            p[0] = floordiv3(-dh);                 // g0
            p[1] = floordiv3(dh);                  // g2
            p[2] = floordiv3(-dw);                 // f0
            p[3] = floordiv3(dw);                  // f2
            p[4] = (dh % 3) * 3 + (dw % 3);        // template case
        }
    }
}

// ---- K1: GEMM A[1152x64] @ XbT^T[64 x 65536] -> T bf16 (R5 verbatim) -----
// grid (512 nt, 9 mt), 256 thr (2x2 wave grid), tile 128m x 128n, K=64.
__global__ __launch_bounds__(256) void k1_gemm(const unsigned short* __restrict__ XbT,
                                               const unsigned short* __restrict__ A,
                                               unsigned short* __restrict__ T) {
    __shared__ union {
        struct { us8 lA[8 * 129]; us8 lB[8 * 129]; } in;   // 33024 B
        unsigned short ot[128 * 132];                       // 33792 B
    } sm;
    const int tid = threadIdx.x;
    const int nt = blockIdx.x;    // 0..511
    const int mt = blockIdx.y;    // 0..8

    #pragma unroll
    for (int i = 0; i < 4; ++i) {
        int gid = i * 256 + tid;
        int row = gid >> 3, ch = gid & 7; // ch fastest -> coalesced 16B/lane
        sm.in.lA[ch * 129 + row] = *reinterpret_cast<const us8*>(
            A + (size_t)(mt * 128 + row) * 64 + ch * 8);
    }
    #pragma unroll
    for (int i = 0; i < 4; ++i) {
        int gid = i * 256 + tid;
        int row = gid >> 3, ch = gid & 7;
        sm.in.lB[ch * 129 + row] = *reinterpret_cast<const us8*>(
            XbT + ((size_t)nt * 128 + row) * 64 + ch * 8);
    }
    __syncthreads();

    const int wave = tid >> 6, lane = tid & 63;
    const int quad = lane >> 4, l15 = lane & 15;
    const int wm = wave & 1, wn = wave >> 1;
    const bf16x8* pA = reinterpret_cast<const bf16x8*>(sm.in.lA);
    const bf16x8* pB = reinterpret_cast<const bf16x8*>(sm.in.lB);

    f32x4 acc[4][4] = {};
    #pragma unroll
    for (int ks = 0; ks < 2; ++ks) {
        const int kg = ks * 4 + quad;
        bf16x8 aF[4], bF[4];
        #pragma unroll
        for (int mi = 0; mi < 4; ++mi)
            aF[mi] = pA[kg * 129 + wm * 64 + mi * 16 + l15];
        #pragma unroll
        for (int ni = 0; ni < 4; ++ni)
            bF[ni] = pB[kg * 129 + wn * 64 + ni * 16 + l15];
        #pragma unroll
        for (int mi = 0; mi < 4; ++mi)
            #pragma unroll
            for (int ni = 0; ni < 4; ++ni)
                acc[mi][ni] = __builtin_amdgcn_mfma_f32_16x16x32_bf16(aF[mi], bF[ni], acc[mi][ni], 0, 0, 0);
    }
    __syncthreads();   // frags consumed; reuse LDS for output tile

    {
        const int mloc = wm * 64 + quad * 4;
        const int nloc = wn * 64 + l15;
        #pragma unroll
        for (int mi = 0; mi < 4; ++mi)
            #pragma unroll
            for (int r = 0; r < 4; ++r) {
                unsigned short* dst = &sm.ot[(mloc + mi * 16 + r) * 132 + nloc];
                #pragma unroll
                for (int ni = 0; ni < 4; ++ni)
                    dst[ni * 16] = f2bf(acc[mi][ni][r]);
            }
    }
    __syncthreads();

    #pragma unroll
    for (int i = 0; i < 8; ++i) {
        int cid = i * 256 + tid;
        int row = cid >> 4, ch = cid & 15;
        us8 v = *reinterpret_cast<const us8*>(&sm.ot[row * 132 + ch * 8]);
        *reinterpret_cast<us8*>(T + (size_t)(mt * 128 + row) * BN + (size_t)nt * 128 + ch * 8) = v;
    }
}

// ---- K2: LDS-staged 36-tap gather + maxpool3 + bias + BN stats -----------
// grid (o=128, b=64), 512 thr, 2 outputs/thread (p and p+16). LDS: 9 planes
// of 33 rows x 40 f32 (4-col pads both sides, row 32 = zeros).
// Gather body templated on (dh%3, dw%3): selector arrays become constexpr.
#define PLS (33 * 40)

template<int RH, int RW>
__device__ __forceinline__ float gather_half(const float* __restrict__ lt,
                                             int p, int qoff,
                                             int g0, int g2, int f0, int f2) {
    // per-y3 / per-x3 selector patterns, keyed by (d mod 3):
    //   sel0[t] = floordiv3(t-d)-floordiv3(-d), sel2[t] = floordiv3(t+d)-floordiv3(d)
    constexpr int C0s[3][3] = {{0,0,0},{0,1,1},{0,0,1}};
    constexpr int C2s[3][3] = {{0,0,0},{0,0,1},{0,1,1}};
    constexpr int R0s[3][3] = {{0,0,0},{0,1,1},{0,0,1}};
    constexpr int R2s[3][3] = {{0,0,0},{0,0,1},{0,1,1}};
    constexpr int NR = RH ? 3 : 1;     // distinct row combos
    constexpr int NC = RW ? 3 : 1;     // distinct col combos
    constexpr bool RB = (RH != 0);     // need second-row variant at all?
    constexpr bool CB = (RW != 0);     // need b-columns at all?

    int rA0 = p + g0;     rA0 = ((unsigned)rA0 < 32u) ? rA0 : 32;
    int rA2 = p + g2;     rA2 = ((unsigned)rA2 < 32u) ? rA2 : 32;
    int rB0 = 0, rB2 = 0;
    if (RB) {
        rB0 = p + g0 + 1; rB0 = ((unsigned)rB0 < 32u) ? rB0 : 32;
        rB2 = p + g2 + 1; rB2 = ((unsigned)rB2 < 32u) ? rB2 : 32;
    }

    float u0[2][3], u1[3], u2[2][3];
    {   // ki = 0 (planes 0..2), rows rA0 (+rB0)
        const float* pl0 = &lt[0 * PLS + qoff + f0];
        const float* pl1 = &lt[1 * PLS + qoff];
        const float* pl2 = &lt[2 * PLS + qoff + f2];
        float pA0a = pl0[rA0 * 40], pA0b = CB ? pl0[rA0 * 40 + 1] : 0.f;
        float sA   = pl1[rA0 * 40];
        float pA2a = pl2[rA0 * 40], pA2b = CB ? pl2[rA0 * 40 + 1] : 0.f;
        float pB0a = 0.f, pB0b = 0.f, sB = 0.f, pB2a = 0.f, pB2b = 0.f;
        if (RB) {
            pB0a = pl0[rB0 * 40]; pB0b = CB ? pl0[rB0 * 40 + 1] : 0.f;
            sB   = pl1[rB0 * 40];
            pB2a = pl2[rB0 * 40]; pB2b = CB ? pl2[rB0 * 40 + 1] : 0.f;
        }
        #pragma unroll
        for (int c = 0; c < NC; ++c) {
            u0[0][c] = (C0s[RW][c] ? pA0b : pA0a) + sA + (C2s[RW][c] ? pA2b : pA2a);
            if (RB)
                u0[1][c] = (C0s[RW][c] ? pB0b : pB0a) + sB + (C2s[RW][c] ? pB2b : pB2a);
        }
    }
    {   // ki = 1 (planes 3..5), row p only (selector identically 0)
        const float* pl0 = &lt[3 * PLS + qoff + f0];
        const float* pl1 = &lt[4 * PLS + qoff];
        const float* pl2 = &lt[5 * PLS + qoff + f2];
        float pa = pl0[p * 40], pb = CB ? pl0[p * 40 + 1] : 0.f;
        float s  = pl1[p * 40];
        float ra = pl2[p * 40], rb = CB ? pl2[p * 40 + 1] : 0.f;
        #pragma unroll
        for (int c = 0; c < NC; ++c)
            u1[c] = (C0s[RW][c] ? pb : pa) + s + (C2s[RW][c] ? rb : ra);
    }
    {   // ki = 2 (planes 6..8), rows rA2 (+rB2)
        const float* pl0 = &lt[6 * PLS + qoff + f0];
        const float* pl1 = &lt[7 * PLS + qoff];
        const float* pl2 = &lt[8 * PLS + qoff + f2];
        float pA0a = pl0[rA2 * 40], pA0b = CB ? pl0[rA2 * 40 + 1] : 0.f;
        float sA   = pl1[rA2 * 40];
        float pA2a = pl2[rA2 * 40], pA2b = CB ? pl2[rA2 * 40 + 1] : 0.f;
        float pB0a = 0.f, pB0b = 0.f, sB = 0.f, pB2a = 0.f, pB2b = 0.f;
        if (RB) {
            pB0a = pl0[rB2 * 40]; pB0b = CB ? pl0[rB2 * 40 + 1] : 0.f;
            sB   = pl1[rB2 * 40];
            pB2a = pl2[rB2 * 40]; pB2b = CB ? pl2[rB2 * 40 + 1] : 0.f;
        }
        #pragma unroll
        for (int c = 0; c < NC; ++c) {
            u2[0][c] = (C0s[RW][c] ? pA0b : pA0a) + sA + (C2s[RW][c] ? pA2b : pA2a);
            if (RB)
                u2[1][c] = (C0s[RW][c] ? pB0b : pB0a) + sB + (C2s[RW][c] ? pB2b : pB2a);
        }
    }

    float best = -3.4e38f;
    #pragma unroll
    for (int r = 0; r < NR; ++r)
        #pragma unroll
        for (int c = 0; c < NC; ++c) {
            float s = u0[R0s[RH][r]][c] + u1[c] + u2[R2s[RH][r]][c];
            best = fmaxf(best, s);
        }
    return best;
}

__global__ __launch_bounds__(512) void k2_gather(const unsigned short* __restrict__ T,
                                                 const float* __restrict__ bias,
                                                 const int* __restrict__ prm,
                                                 float* __restrict__ out,
                                                 float* __restrict__ stats) {
    __shared__ float lt[9 * PLS + 4];
    __shared__ float red[16];
    const int tid = threadIdx.x;
    const int o = blockIdx.x, b = blockIdx.y;

    // zero pad columns (rows 0..31, cols {0..3, 36..39})
    #pragma unroll
    for (int it = 0; it < 5; ++it) {
        int i = it * 512 + tid;
        if (i < 9 * 32 * 8) {
            int pr = i >> 3, c = i & 7;
            int kk = pr >> 5, r = pr & 31;
            lt[kk * PLS + r * 40 + (c < 4 ? c : c + 32)] = 0.f;
        }
    }
    // zero row 32 of each plane; slack zeroed separately (in-bounds)
    if (tid < 9 * 40) {
        int kk = tid / 40, c = tid - kk * 40;
        lt[kk * PLS + 32 * 40 + c] = 0.f;
    }
    if (tid < 4) lt[9 * PLS + tid] = 0.f;
    // stage 9 planes (1024 bf16 contiguous each) -> f32 padded rows
    const unsigned short* Tb = T + (size_t)o * BN + (size_t)b * 1024;
    for (int i = tid; i < 9 * 128; i += 512) {
        int kk = i >> 7, c8 = i & 127;
        us8 v = *reinterpret_cast<const us8*>(Tb + (size_t)kk * 128 * BN + c8 * 8);
        int r = c8 >> 2, cb = (c8 & 3) * 8;
        float* dst = &lt[kk * PLS + r * 40 + 4 + cb];
        f32x4 lo, hi;
        lo[0] = bf2f(v[0]); lo[1] = bf2f(v[1]); lo[2] = bf2f(v[2]); lo[3] = bf2f(v[3]);
        hi[0] = bf2f(v[4]); hi[1] = bf2f(v[5]); hi[2] = bf2f(v[6]); hi[3] = bf2f(v[7]);
        *reinterpret_cast<f32x4*>(dst) = lo;
        *reinterpret_cast<f32x4*>(dst + 4) = hi;
    }
    __syncthreads();

    // block-uniform gather params (precomputed in k0, scalar loads)
    const int* pb = prm + b * 8;
    const int g0 = pb[0], g2 = pb[1], f0 = pb[2], f2 = pb[3], cs = pb[4];
    const int q = tid & 31, pbase = tid >> 5;   // pbase 0..15
    const int qoff = q + 4;
    const float bias_o = bias[o];

    float v0 = 0.f, v1 = 0.f;
    #define GCASE(n) case n: \
        v0 = gather_half<(n)/3, (n)%3>(lt, pbase,      qoff, g0, g2, f0, f2); \
        v1 = gather_half<(n)/3, (n)%3>(lt, pbase + 16, qoff, g0, g2, f0, f2); \
        break;
    switch (cs) {
        GCASE(0) GCASE(1) GCASE(2) GCASE(3)
        GCASE(4) GCASE(5) GCASE(6) GCASE(7)
        default:
            v0 = gather_half<2, 2>(lt, pbase,      qoff, g0, g2, f0, f2);
            v1 = gather_half<2, 2>(lt, pbase + 16, qoff, g0, g2, f0, f2);
            break;
    }
    #undef GCASE

    float val0 = v0 + bias_o;
    float val1 = v1 + bias_o;
    out[(((size_t)b * 128 + o) * 32 + pbase) * 32 + q] = val0;
    out[(((size_t)b * 128 + o) * 32 + pbase + 16) * 32 + q] = val1;
    float s1 = val0 + val1;
    float s2 = val0 * val0 + val1 * val1;

    // stats: wave reduce -> LDS -> block reduce -> 2 atomics
    #pragma unroll
    for (int m = 32; m >= 1; m >>= 1) {
        s1 += __shfl_xor(s1, m, 64);
        s2 += __shfl_xor(s2, m, 64);
    }
    if ((tid & 63) == 0) {
        red[tid >> 6] = s1;
        red[8 + (tid >> 6)] = s2;
    }
    __syncthreads();
    if (tid < 64) {
        float a1 = (tid < 8) ? red[tid] : 0.f;
        float a2 = (tid < 8) ? red[8 + tid] : 0.f;
        #pragma unroll
        for (int m = 4; m >= 1; m >>= 1) {
            a1 += __shfl_xor(a1, m, 64);
            a2 += __shfl_xor(a2, m, 64);
        }
        if (tid == 0) {
            atomicAdd(&stats[o], a1);
            atomicAdd(&stats[128 + o], a2);
        }
    }
}

// ---- K3: BN finalize + affine + relu, in-place on d_out ------------------
__global__ __launch_bounds__(256) void k3_bn(float4* __restrict__ out,
                                             const float* __restrict__ stats,
                                             const float* __restrict__ gamma,
                                             const float* __restrict__ beta) {
    int i4 = blockIdx.x * 256 + threadIdx.x;   // 0..2097151
    int o = (i4 >> 8) & 127;
    const float invN = 1.0f / 65536.0f;
    float mean = stats[o] * invN;
    float var = stats[128 + o] * invN - mean * mean;
    float inv = rsqrtf(var + 1e-5f);
    float sc = gamma[o] * inv;
    float sh = beta[o] - mean * sc;
    float4 v = out[i4];
    v.x = fmaxf(fmaf(v.x, sc, sh), 0.f);
    v.y = fmaxf(fmaf(v.y, sc, sh), 0.f);
    v.z = fmaxf(fmaf(v.z, sc, sh), 0.f);
    v.w = fmaxf(fmaf(v.w, sc, sh), 0.f);
    out[i4] = v;
}

extern "C" void kernel_launch(void* const* d_in, const int* in_sizes, int n_in,
                              void* d_out, int out_size, void* d_ws, size_t ws_size,
                              hipStream_t stream) {
    const float* x     = (const float*)d_in[0];
    const int*   h     = (const int*)d_in[1];
    const int*   w     = (const int*)d_in[2];
    const float* wt    = (const float*)d_in[3];
    const float* bias  = (const float*)d_in[4];
    const float* gamma = (const float*)d_in[5];
    const float* beta  = (const float*)d_in[6];
    float* out = (float*)d_out;
    char* ws = (char*)d_ws;

    float*          stats = (float*)(ws + 0);
    int*            prm   = (int*)(ws + 1024);
    unsigned short* A     = (unsigned short*)(ws + 4096);
    unsigned short* XbT   = (unsigned short*)(ws + 151552);
    unsigned short* T     = (unsigned short*)(ws + 8540160);

    k0_all<<<1313, 256, 0, stream>>>(x, wt, h, w, XbT, A, stats, prm);
    k1_gemm<<<dim3(512, 9), 256, 0, stream>>>(XbT, A, T);
    k2_gather<<<dim3(128, 64), 512, 0, stream>>>(T, bias, prm, out, stats);
    k3_bn<<<8192, 256, 0, stream>>>((float4*)out, stats, gamma, beta);
}

// Round 3
// 152.848 us; speedup vs baseline: 1.0725x; 1.0656x over previous
//
#include <hip/hip_runtime.h>
#include <hip/hip_bf16.h>

// SizeInvBlock: upsample3x(nearest) -> per-sample dilated 3x3 conv -> maxpool3 -> BN(train) -> relu
// Factorization: conv on the 3x-upsampled image only samples original 32x32 pixels:
//   out[o,y,x] = bias[o] + sum_{ki,kj} T[kikj][o, r_ki(y), c_kj(x)]
//   T[kikj][o,i,j] = sum_c W[o,c,ki,kj] * X[c,i,j]   (one GEMM, 9x fewer FLOPs than direct conv)
// R10: k2 gather specialized on (dh%3, dw%3) -> 9 compile-time cases (verified).
// R11 (FAILED): cooperative-launch k2+k3 fusion -> launch rejected, out stayed zero. Reverted.
// R12: k2 LDS staged in bf16 (was f32). Staging becomes a pure us8 copy
//   (no unpack VALU, one ds_write_b128); gather converts per-tap (1 shift).
//   LDS 47.6KB -> 28.6KB per block => occupancy cap 2 -> 4+ blocks/CU
//   (k2 was latency-bound: VALU 57%, HBM 28%, occ 46%). 8-col bf16 pads on
//   both sides keep every staged us8 16B-aligned.
//
// ws layout (bytes):
//   [0,      1024)    stats: sum[128], sumsq[128] (f32, atomic; zeroed by k0_all)
//   [1024,   3072)    prm: per-b gather params int[64][8] = {g0,g2,f0,f2,case,...}
//   [4096,   151552)  A bf16 [1152][64]   (m = (ki*3+kj)*128 + o, k = cin)
//   [151552, 8540160) XbT bf16 [64 b][1024 n][64 c]
//   [8540160,159535104) T bf16 [1152][65536]  (n = b*1024 + i*32 + j)

typedef __attribute__((ext_vector_type(8))) short bf16x8;
typedef __attribute__((ext_vector_type(4))) float f32x4;
typedef __attribute__((ext_vector_type(8))) unsigned short us8;

#define BN 65536   // T n-dimension (all 64 samples)

__device__ __forceinline__ unsigned short f2bf(float f) {
    unsigned u = __float_as_uint(f);
    u += 0x7fffu + ((u >> 16) & 1u);
    return (unsigned short)(u >> 16);
}
__device__ __forceinline__ float bf2f(unsigned short s) {
    return __uint_as_float(((unsigned)s) << 16);
}
__device__ __forceinline__ int floordiv3(int t) {
    return (t >= 0) ? (t / 3) : -((2 - t) / 3);
}

// ---- K0: merged prep: X transpose->bf16, W pack->bf16, stats zero, prm ---
// blocks 0..1023: XbT; 1024..1311: A; 1312: stats zero + per-b gather params.
__global__ __launch_bounds__(256) void k0_all(const float* __restrict__ x,
                                              const float* __restrict__ w,
                                              const int* __restrict__ hh,
                                              const int* __restrict__ ww,
                                              unsigned short* __restrict__ xbt,
                                              unsigned short* __restrict__ A,
                                              float* __restrict__ stats,
                                              int* __restrict__ prm) {
    const int bid = blockIdx.x;
    const int tid = threadIdx.x;
    if (bid < 1024) {
        const int n = (bid & 15) * 64 + (tid & 63);
        const int cg = tid >> 6;
        const int b = bid >> 4;
        #pragma unroll
        for (int j2 = 0; j2 < 2; ++j2) {
            int c8 = cg * 2 + j2;                 // 0..7
            us8 r;
            #pragma unroll
            for (int j = 0; j < 8; ++j)
                r[j] = f2bf(x[(((b << 6) + c8 * 8 + j) << 10) + n]);
            *reinterpret_cast<us8*>(xbt + ((size_t)(b << 10) + n) * 64 + c8 * 8) = r;
        }
    } else if (bid < 1312) {
        int gid = (bid - 1024) * 256 + tid;       // < 73728
        int m = gid >> 6, c = gid & 63;
        int kk = m >> 7, o = m & 127;
        A[gid] = f2bf(w[(o * 64 + c) * 9 + kk]);
    } else {
        stats[tid] = 0.f;                          // 256 floats = sum+sumsq
        if (tid < 64) {
            int dh = 96 / hh[tid]; if (dh < 1) dh = 1;
            int dw = 96 / ww[tid]; if (dw < 1) dw = 1;
            int* p = prm + tid * 8;
            p[0] = floordiv3(-dh);                 // g0
            p[1] = floordiv3(dh);                  // g2
            p[2] = floordiv3(-dw);                 // f0
            p[3] = floordiv3(dw);                  // f2
            p[4] = (dh % 3) * 3 + (dw % 3);        // template case
        }
    }
}

// ---- K1: GEMM A[1152x64] @ XbT^T[64 x 65536] -> T bf16 (R5 verbatim) -----
// grid (512 nt, 9 mt), 256 thr (2x2 wave grid), tile 128m x 128n, K=64.
__global__ __launch_bounds__(256) void k1_gemm(const unsigned short* __restrict__ XbT,
                                               const unsigned short* __restrict__ A,
                                               unsigned short* __restrict__ T) {
    __shared__ union {
        struct { us8 lA[8 * 129]; us8 lB[8 * 129]; } in;   // 33024 B
        unsigned short ot[128 * 132];                       // 33792 B
    } sm;
    const int tid = threadIdx.x;
    const int nt = blockIdx.x;    // 0..511
    const int mt = blockIdx.y;    // 0..8

    #pragma unroll
    for (int i = 0; i < 4; ++i) {
        int gid = i * 256 + tid;
        int row = gid >> 3, ch = gid & 7; // ch fastest -> coalesced 16B/lane
        sm.in.lA[ch * 129 + row] = *reinterpret_cast<const us8*>(
            A + (size_t)(mt * 128 + row) * 64 + ch * 8);
    }
    #pragma unroll
    for (int i = 0; i < 4; ++i) {
        int gid = i * 256 + tid;
        int row = gid >> 3, ch = gid & 7;
        sm.in.lB[ch * 129 + row] = *reinterpret_cast<const us8*>(
            XbT + ((size_t)nt * 128 + row) * 64 + ch * 8);
    }
    __syncthreads();

    const int wave = tid >> 6, lane = tid & 63;
    const int quad = lane >> 4, l15 = lane & 15;
    const int wm = wave & 1, wn = wave >> 1;
    const bf16x8* pA = reinterpret_cast<const bf16x8*>(sm.in.lA);
    const bf16x8* pB = reinterpret_cast<const bf16x8*>(sm.in.lB);

    f32x4 acc[4][4] = {};
    #pragma unroll
    for (int ks = 0; ks < 2; ++ks) {
        const int kg = ks * 4 + quad;
        bf16x8 aF[4], bF[4];
        #pragma unroll
        for (int mi = 0; mi < 4; ++mi)
            aF[mi] = pA[kg * 129 + wm * 64 + mi * 16 + l15];
        #pragma unroll
        for (int ni = 0; ni < 4; ++ni)
            bF[ni] = pB[kg * 129 + wn * 64 + ni * 16 + l15];
        #pragma unroll
        for (int mi = 0; mi < 4; ++mi)
            #pragma unroll
            for (int ni = 0; ni < 4; ++ni)
                acc[mi][ni] = __builtin_amdgcn_mfma_f32_16x16x32_bf16(aF[mi], bF[ni], acc[mi][ni], 0, 0, 0);
    }
    __syncthreads();   // frags consumed; reuse LDS for output tile

    {
        const int mloc = wm * 64 + quad * 4;
        const int nloc = wn * 64 + l15;
        #pragma unroll
        for (int mi = 0; mi < 4; ++mi)
            #pragma unroll
            for (int r = 0; r < 4; ++r) {
                unsigned short* dst = &sm.ot[(mloc + mi * 16 + r) * 132 + nloc];
                #pragma unroll
                for (int ni = 0; ni < 4; ++ni)
                    dst[ni * 16] = f2bf(acc[mi][ni][r]);
            }
    }
    __syncthreads();

    #pragma unroll
    for (int i = 0; i < 8; ++i) {
        int cid = i * 256 + tid;
        int row = cid >> 4, ch = cid & 15;
        us8 v = *reinterpret_cast<const us8*>(&sm.ot[row * 132 + ch * 8]);
        *reinterpret_cast<us8*>(T + (size_t)(mt * 128 + row) * BN + (size_t)nt * 128 + ch * 8) = v;
    }
}

// ---- K2: LDS-staged (bf16) 36-tap gather + maxpool3 + bias + BN stats ----
// grid (o=128, b=64), 512 thr, 2 outputs/thread (p and p+16). LDS: 9 planes
// of 33 rows x 48 bf16 (8-col pads both sides -> 16B-aligned us8 stores,
// row 32 = zeros). Taps converted bf16->f32 on read (1 shift each).
#define PLSB (33 * 48)

template<int RH, int RW>
__device__ __forceinline__ float gather_half(const unsigned short* __restrict__ lt,
                                             int p, int qoff,
                                             int g0, int g2, int f0, int f2) {
    // per-y3 / per-x3 selector patterns, keyed by (d mod 3):
    //   sel0[t] = floordiv3(t-d)-floordiv3(-d), sel2[t] = floordiv3(t+d)-floordiv3(d)
    constexpr int C0s[3][3] = {{0,0,0},{0,1,1},{0,0,1}};
    constexpr int C2s[3][3] = {{0,0,0},{0,0,1},{0,1,1}};
    constexpr int R0s[3][3] = {{0,0,0},{0,1,1},{0,0,1}};
    constexpr int R2s[3][3] = {{0,0,0},{0,0,1},{0,1,1}};
    constexpr int NR = RH ? 3 : 1;     // distinct row combos
    constexpr int NC = RW ? 3 : 1;     // distinct col combos
    constexpr bool RB = (RH != 0);     // need second-row variant at all?
    constexpr bool CB = (RW != 0);     // need b-columns at all?

    int rA0 = p + g0;     rA0 = ((unsigned)rA0 < 32u) ? rA0 : 32;
    int rA2 = p + g2;     rA2 = ((unsigned)rA2 < 32u) ? rA2 : 32;
    int rB0 = 0, rB2 = 0;
    if (RB) {
        rB0 = p + g0 + 1; rB0 = ((unsigned)rB0 < 32u) ? rB0 : 32;
        rB2 = p + g2 + 1; rB2 = ((unsigned)rB2 < 32u) ? rB2 : 32;
    }

    float u0[2][3], u1[3], u2[2][3];
    {   // ki = 0 (planes 0..2), rows rA0 (+rB0)
        const unsigned short* pl0 = &lt[0 * PLSB + qoff + f0];
        const unsigned short* pl1 = &lt[1 * PLSB + qoff];
        const unsigned short* pl2 = &lt[2 * PLSB + qoff + f2];
        float pA0a = bf2f(pl0[rA0 * 48]), pA0b = CB ? bf2f(pl0[rA0 * 48 + 1]) : 0.f;
        float sA   = bf2f(pl1[rA0 * 48]);
        float pA2a = bf2f(pl2[rA0 * 48]), pA2b = CB ? bf2f(pl2[rA0 * 48 + 1]) : 0.f;
        float pB0a = 0.f, pB0b = 0.f, sB = 0.f, pB2a = 0.f, pB2b = 0.f;
        if (RB) {
            pB0a = bf2f(pl0[rB0 * 48]); pB0b = CB ? bf2f(pl0[rB0 * 48 + 1]) : 0.f;
            sB   = bf2f(pl1[rB0 * 48]);
            pB2a = bf2f(pl2[rB0 * 48]); pB2b = CB ? bf2f(pl2[rB0 * 48 + 1]) : 0.f;
        }
        #pragma unroll
        for (int c = 0; c < NC; ++c) {
            u0[0][c] = (C0s[RW][c] ? pA0b : pA0a) + sA + (C2s[RW][c] ? pA2b : pA2a);
            if (RB)
                u0[1][c] = (C0s[RW][c] ? pB0b : pB0a) + sB + (C2s[RW][c] ? pB2b : pB2a);
        }
    }
    {   // ki = 1 (planes 3..5), row p only (selector identically 0)
        const unsigned short* pl0 = &lt[3 * PLSB + qoff + f0];
        const unsigned short* pl1 = &lt[4 * PLSB + qoff];
        const unsigned short* pl2 = &lt[5 * PLSB + qoff + f2];
        float pa = bf2f(pl0[p * 48]), pb = CB ? bf2f(pl0[p * 48 + 1]) : 0.f;
        float s  = bf2f(pl1[p * 48]);
        float ra = bf2f(pl2[p * 48]), rb = CB ? bf2f(pl2[p * 48 + 1]) : 0.f;
        #pragma unroll
        for (int c = 0; c < NC; ++c)
            u1[c] = (C0s[RW][c] ? pb : pa) + s + (C2s[RW][c] ? rb : ra);
    }
    {   // ki = 2 (planes 6..8), rows rA2 (+rB2)
        const unsigned short* pl0 = &lt[6 * PLSB + qoff + f0];
        const unsigned short* pl1 = &lt[7 * PLSB + qoff];
        const unsigned short* pl2 = &lt[8 * PLSB + qoff + f2];
        float pA0a = bf2f(pl0[rA2 * 48]), pA0b = CB ? bf2f(pl0[rA2 * 48 + 1]) : 0.f;
        float sA   = bf2f(pl1[rA2 * 48]);
        float pA2a = bf2f(pl2[rA2 * 48]), pA2b = CB ? bf2f(pl2[rA2 * 48 + 1]) : 0.f;
        float pB0a = 0.f, pB0b = 0.f, sB = 0.f, pB2a = 0.f, pB2b = 0.f;
        if (RB) {
            pB0a = bf2f(pl0[rB2 * 48]); pB0b = CB ? bf2f(pl0[rB2 * 48 + 1]) : 0.f;
            sB   = bf2f(pl1[rB2 * 48]);
            pB2a = bf2f(pl2[rB2 * 48]); pB2b = CB ? bf2f(pl2[rB2 * 48 + 1]) : 0.f;
        }
        #pragma unroll
        for (int c = 0; c < NC; ++c) {
            u2[0][c] = (C0s[RW][c] ? pA0b : pA0a) + sA + (C2s[RW][c] ? pA2b : pA2a);
            if (RB)
                u2[1][c] = (C0s[RW][c] ? pB0b : pB0a) + sB + (C2s[RW][c] ? pB2b : pB2a);
        }
    }

    float best = -3.4e38f;
    #pragma unroll
    for (int r = 0; r < NR; ++r)
        #pragma unroll
        for (int c = 0; c < NC; ++c) {
            float s = u0[R0s[RH][r]][c] + u1[c] + u2[R2s[RH][r]][c];
            best = fmaxf(best, s);
        }
    return best;
}

__global__ __launch_bounds__(512) void k2_gather(const unsigned short* __restrict__ T,
                                                 const float* __restrict__ bias,
                                                 const int* __restrict__ prm,
                                                 float* __restrict__ out,
                                                 float* __restrict__ stats) {
    __shared__ __align__(16) unsigned short lt[9 * PLSB + 8];
    __shared__ float red[16];
    const int tid = threadIdx.x;
    const int o = blockIdx.x, b = blockIdx.y;

    // zero pad columns: 9 planes x 32 rows x 2 sides, one us8 (8 bf16) each.
    // side 0 = cols 0..7 (byte 0), side 1 = cols 40..47 (byte 80) - 16B aligned.
    static const us8 z8 = {0, 0, 0, 0, 0, 0, 0, 0};
    {
        int i = tid;                               // 0..511
        int kk = i >> 6, rem = i & 63, r = rem >> 1, side = rem & 1;
        *reinterpret_cast<us8*>(&lt[kk * PLSB + r * 48 + side * 40]) = z8;
        if (tid < 64) {
            i = tid + 512;                         // 512..575
            kk = i >> 6; rem = i & 63; r = rem >> 1; side = rem & 1;
            *reinterpret_cast<us8*>(&lt[kk * PLSB + r * 48 + side * 40]) = z8;
        }
    }
    // zero row 32 of each plane: 9 x 48 bf16 = 54 us8; plus 8-el slack.
    if (tid < 54) {
        int kk = tid / 6, c = tid - kk * 6;
        *reinterpret_cast<us8*>(&lt[kk * PLSB + 32 * 48 + c * 8]) = z8;
    }
    if (tid == 63) *reinterpret_cast<us8*>(&lt[9 * PLSB]) = z8;

    // stage 9 planes (1024 bf16 contiguous each) -> bf16 padded rows (pure copy)
    const unsigned short* Tb = T + (size_t)o * BN + (size_t)b * 1024;
    {
        int i = tid;                               // pass 1: 0..511
        int kk = i >> 7, c8 = i & 127;
        us8 v = *reinterpret_cast<const us8*>(Tb + (size_t)kk * (128 * BN) + c8 * 8);
        *reinterpret_cast<us8*>(&lt[kk * PLSB + (c8 >> 2) * 48 + 8 + (c8 & 3) * 8]) = v;
        i = tid + 512;                             // pass 2: 512..1023
        kk = i >> 7; c8 = i & 127;
        us8 v2 = *reinterpret_cast<const us8*>(Tb + (size_t)kk * (128 * BN) + c8 * 8);
        *reinterpret_cast<us8*>(&lt[kk * PLSB + (c8 >> 2) * 48 + 8 + (c8 & 3) * 8]) = v2;
        if (tid < 128) {                           // pass 3: 1024..1151 (kk = 8)
            c8 = tid;
            us8 v3 = *reinterpret_cast<const us8*>(Tb + (size_t)8 * (128 * BN) + c8 * 8);
            *reinterpret_cast<us8*>(&lt[8 * PLSB + (c8 >> 2) * 48 + 8 + (c8 & 3) * 8]) = v3;
        }
    }
    __syncthreads();

    // block-uniform gather params (precomputed in k0, scalar loads)
    const int* pb = prm + b * 8;
    const int g0 = pb[0], g2 = pb[1], f0 = pb[2], f2 = pb[3], cs = pb[4];
    const int q = tid & 31, pbase = tid >> 5;   // pbase 0..15
    const int qoff = q + 8;
    const float bias_o = bias[o];

    float v0 = 0.f, v1 = 0.f;
    #define GCASE(n) case n: \
        v0 = gather_half<(n)/3, (n)%3>(lt, pbase,      qoff, g0, g2, f0, f2); \
        v1 = gather_half<(n)/3, (n)%3>(lt, pbase + 16, qoff, g0, g2, f0, f2); \
        break;
    switch (cs) {
        GCASE(0) GCASE(1) GCASE(2) GCASE(3)
        GCASE(4) GCASE(5) GCASE(6) GCASE(7)
        default:
            v0 = gather_half<2, 2>(lt, pbase,      qoff, g0, g2, f0, f2);
            v1 = gather_half<2, 2>(lt, pbase + 16, qoff, g0, g2, f0, f2);
            break;
    }
    #undef GCASE

    float val0 = v0 + bias_o;
    float val1 = v1 + bias_o;
    out[(((size_t)b * 128 + o) * 32 + pbase) * 32 + q] = val0;
    out[(((size_t)b * 128 + o) * 32 + pbase + 16) * 32 + q] = val1;
    float s1 = val0 + val1;
    float s2 = val0 * val0 + val1 * val1;

    // stats: wave reduce -> LDS -> block reduce -> 2 atomics
    #pragma unroll
    for (int m = 32; m >= 1; m >>= 1) {
        s1 += __shfl_xor(s1, m, 64);
        s2 += __shfl_xor(s2, m, 64);
    }
    if ((tid & 63) == 0) {
        red[tid >> 6] = s1;
        red[8 + (tid >> 6)] = s2;
    }
    __syncthreads();
    if (tid < 64) {
        float a1 = (tid < 8) ? red[tid] : 0.f;
        float a2 = (tid < 8) ? red[8 + tid] : 0.f;
        #pragma unroll
        for (int m = 4; m >= 1; m >>= 1) {
            a1 += __shfl_xor(a1, m, 64);
            a2 += __shfl_xor(a2, m, 64);
        }
        if (tid == 0) {
            atomicAdd(&stats[o], a1);
            atomicAdd(&stats[128 + o], a2);
        }
    }
}

// ---- K3: BN finalize + affine + relu, in-place on d_out ------------------
__global__ __launch_bounds__(256) void k3_bn(float4* __restrict__ out,
                                             const float* __restrict__ stats,
                                             const float* __restrict__ gamma,
                                             const float* __restrict__ beta) {
    int i4 = blockIdx.x * 256 + threadIdx.x;   // 0..2097151
    int o = (i4 >> 8) & 127;
    const float invN = 1.0f / 65536.0f;
    float mean = stats[o] * invN;
    float var = stats[128 + o] * invN - mean * mean;
    float inv = rsqrtf(var + 1e-5f);
    float sc = gamma[o] * inv;
    float sh = beta[o] - mean * sc;
    float4 v = out[i4];
    v.x = fmaxf(fmaf(v.x, sc, sh), 0.f);
    v.y = fmaxf(fmaf(v.y, sc, sh), 0.f);
    v.z = fmaxf(fmaf(v.z, sc, sh), 0.f);
    v.w = fmaxf(fmaf(v.w, sc, sh), 0.f);
    out[i4] = v;
}

extern "C" void kernel_launch(void* const* d_in, const int* in_sizes, int n_in,
                              void* d_out, int out_size, void* d_ws, size_t ws_size,
                              hipStream_t stream) {
    const float* x     = (const float*)d_in[0];
    const int*   h     = (const int*)d_in[1];
    const int*   w     = (const int*)d_in[2];
    const float* wt    = (const float*)d_in[3];
    const float* bias  = (const float*)d_in[4];
    const float* gamma = (const float*)d_in[5];
    const float* beta  = (const float*)d_in[6];
    float* out = (float*)d_out;
    char* ws = (char*)d_ws;

    float*          stats = (float*)(ws + 0);
    int*            prm   = (int*)(ws + 1024);
    unsigned short* A     = (unsigned short*)(ws + 4096);
    unsigned short* XbT   = (unsigned short*)(ws + 151552);
    unsigned short* T     = (unsigned short*)(ws + 8540160);

    k0_all<<<1313, 256, 0, stream>>>(x, wt, h, w, XbT, A, stats, prm);
    k1_gemm<<<dim3(512, 9), 256, 0, stream>>>(XbT, A, T);
    k2_gather<<<dim3(128, 64), 512, 0, stream>>>(T, bias, prm, out, stats);
    k3_bn<<<8192, 256, 0, stream>>>((float4*)out, stats, gamma, beta);
}